// Round 4
// baseline (767.705 us; speedup 1.0000x reference)
//
#include <hip/hip_runtime.h>
#include <hip/hip_bf16.h>
#include <stdint.h>

// QuantLinear GPTQ 4-bit: out[8192,11008] = x[8192,4096] . W[4096,11008] + bias
#define M_DIM 8192
#define K_DIM 4096
#define N_DIM 11008

typedef __bf16 bf16x8 __attribute__((ext_vector_type(8)));
typedef float f32x16 __attribute__((ext_vector_type(16)));

typedef __attribute__((address_space(1))) const void global_cvoid;
typedef __attribute__((address_space(3))) void lds_void;

__device__ __forceinline__ unsigned short f2bf(float f) {
  unsigned int u = __float_as_uint(f);
  u += 0x7fffu + ((u >> 16) & 1u);
  return (unsigned short)(u >> 16);
}

__device__ __forceinline__ void gload_lds16(const void* g, void* l) {
  __builtin_amdgcn_global_load_lds((global_cvoid*)g, (lds_void*)l, 16, 0, 0);
}

// ---------------- stage 1: x fp32 -> bf16 ----------------
__global__ void k_convert_x(const float* __restrict__ x, unsigned short* __restrict__ xb) {
  const int nthreads = gridDim.x * blockDim.x;
  int tid = blockIdx.x * blockDim.x + threadIdx.x;
  const int n8 = (M_DIM * K_DIM) / 8;
  for (int i = tid; i < n8; i += nthreads) {
    const float4* p = (const float4*)x + (size_t)i * 2;
    float4 a = p[0], b = p[1];
    union { unsigned short h[8]; uint4 u; } r;
    r.h[0] = f2bf(a.x); r.h[1] = f2bf(a.y); r.h[2] = f2bf(a.z); r.h[3] = f2bf(a.w);
    r.h[4] = f2bf(b.x); r.h[5] = f2bf(b.y); r.h[6] = f2bf(b.z); r.h[7] = f2bf(b.w);
    ((uint4*)xb)[i] = r.u;
  }
}

// ---------------- stage 2: dequant W -> bf16 W^T [N][K] ----------------
__global__ void k_dequant_w(const int* __restrict__ qw, const int* __restrict__ qz,
                            const float* __restrict__ sc, unsigned short* __restrict__ wt) {
  int n = blockIdx.x * blockDim.x + threadIdx.x;
  int k8_0 = blockIdx.y * 8;
  int g = (k8_0 * 8) >> 7;
  float s = sc[g * N_DIM + n];
  int zq = (qz[g * (N_DIM / 8) + (n >> 3)] >> ((n & 7) * 4)) & 15;
  float zs = s * (float)zq;
  #pragma unroll
  for (int i = 0; i < 8; ++i) {
    int k8 = k8_0 + i;
    int w = qw[(size_t)k8 * N_DIM + n];
    union { unsigned short h[8]; uint4 u; } r;
    #pragma unroll
    for (int j = 0; j < 8; ++j) {
      float v = s * (float)((w >> (4 * j)) & 15) - zs;
      r.h[j] = f2bf(v);
    }
    *(uint4*)(wt + (size_t)n * K_DIM + (size_t)k8 * 8) = r.u;
  }
}

// ---------------- stage 3: 256x256 8-phase GEMM, 32x32x16 MFMA ----------------
// A = Xb [M][K], B = Wt [N][K]. 8 waves (2Mx4N), per-wave 128x64 out.
// Phase = one 16-wide K-slice: 8 independent MFMA (4mi x 2nj).
// B-frags for all 4 slices register-cached (read P1/P2 tops); A-frags read
// per-phase (NEXTR of previous phase). Race-free stage order: a region is
// staged only >=1 lgkm-drain + barrier after its last read:
//   buf0-B reads drain P2 -> staged P3/P4 | buf0-A drains P4 -> staged P5/P6
//   buf1-B drains P6 -> staged P7/P8      | buf1-A drains P8 -> staged P1/P2
// LDS swizzle: 16B slot ^= (row&7) on stage-source and reads (involution).

#define MFMAQ(ks) do { \
  __builtin_amdgcn_s_setprio(1); \
  acc[0][0] = __builtin_amdgcn_mfma_f32_32x32x16_bf16(afr[0], bfr[0][ks], acc[0][0], 0, 0, 0); \
  acc[0][1] = __builtin_amdgcn_mfma_f32_32x32x16_bf16(afr[0], bfr[1][ks], acc[0][1], 0, 0, 0); \
  acc[1][0] = __builtin_amdgcn_mfma_f32_32x32x16_bf16(afr[1], bfr[0][ks], acc[1][0], 0, 0, 0); \
  acc[1][1] = __builtin_amdgcn_mfma_f32_32x32x16_bf16(afr[1], bfr[1][ks], acc[1][1], 0, 0, 0); \
  acc[2][0] = __builtin_amdgcn_mfma_f32_32x32x16_bf16(afr[2], bfr[0][ks], acc[2][0], 0, 0, 0); \
  acc[2][1] = __builtin_amdgcn_mfma_f32_32x32x16_bf16(afr[2], bfr[1][ks], acc[2][1], 0, 0, 0); \
  acc[3][0] = __builtin_amdgcn_mfma_f32_32x32x16_bf16(afr[3], bfr[0][ks], acc[3][0], 0, 0, 0); \
  acc[3][1] = __builtin_amdgcn_mfma_f32_32x32x16_bf16(afr[3], bfr[1][ks], acc[3][1], 0, 0, 0); \
  __builtin_amdgcn_s_setprio(0); \
} while (0)

// A fragments (4) for K-slice ks of buffer buf
#define LOADA(buf, ks) do { \
  const unsigned short* ah_ = sh + (((buf)*2)*2 + wm) * 8192; \
  afr[0] = *(const bf16x8*)(const void*)(ah_ + (aBase0 ^ ((ks) << 4))); \
  afr[1] = *(const bf16x8*)(const void*)(ah_ + (aBase1 ^ ((ks) << 4))); \
  afr[2] = *(const bf16x8*)(const void*)(ah_ + (aBase2 ^ ((ks) << 4))); \
  afr[3] = *(const bf16x8*)(const void*)(ah_ + (aBase3 ^ ((ks) << 4))); \
} while (0)

// B fragments for K-slices 2h, 2h+1 of buffer buf (4 reads)
#define LOADB2(buf, h) do { \
  const unsigned short* bh_ = sh + (((buf)*2 + 1)*2 + (wn >> 1)) * 8192; \
  bfr[0][2*(h)]   = *(const bf16x8*)(const void*)(bh_ + (bBase0 ^ ((2*(h))   << 4))); \
  bfr[0][2*(h)+1] = *(const bf16x8*)(const void*)(bh_ + (bBase0 ^ ((2*(h)+1) << 4))); \
  bfr[1][2*(h)]   = *(const bf16x8*)(const void*)(bh_ + (bBase1 ^ ((2*(h))   << 4))); \
  bfr[1][2*(h)+1] = *(const bf16x8*)(const void*)(bh_ + (bBase1 ^ ((2*(h)+1) << 4))); \
} while (0)

#define STAGE(buf, ab, half, kt) do { \
  const unsigned short* g_ = ((ab) ? pB : pA) + ((size_t)(half) * 128) * K_DIM + (kt) * 64; \
  unsigned short* l_ = sh + ((((buf)*2 + (ab))*2 + (half)) * 8192) + w * 1024; \
  gload_lds16(g_, l_); \
  gload_lds16(g_ + 8 * K_DIM, l_ + 512); \
} while (0)

#define NOSTMT ((void)0)
#define WAIT_VM4 asm volatile("s_waitcnt vmcnt(4)" ::: "memory")
#define WAIT_VM0 asm volatile("s_waitcnt vmcnt(0)" ::: "memory")

// phase: frag reads (pre-barrier) | stage issue -> barrier -> lgkm drain ->
//        8 MFMA -> [counted vmcnt] -> next-phase A reads -> barrier
#define PHASE(ks, TOPR, S1, VW, NEXTR) do { \
  TOPR; \
  S1; \
  __builtin_amdgcn_s_barrier(); \
  asm volatile("s_waitcnt lgkmcnt(0)" ::: "memory"); \
  __builtin_amdgcn_sched_barrier(0); \
  MFMAQ(ks); \
  VW; \
  NEXTR; \
  __builtin_amdgcn_sched_barrier(0); \
  __builtin_amdgcn_s_barrier(); \
  asm volatile("" ::: "memory"); \
} while (0)

__global__ __launch_bounds__(512, 2) void k_gemm(const unsigned short* __restrict__ Xb,
                                                 const unsigned short* __restrict__ Wt,
                                                 const float* __restrict__ bias,
                                                 float* __restrict__ out) {
  __shared__ __align__(16) unsigned short sh[2 * 2 * 2 * 8192];  // 128 KiB

  const int nwg = gridDim.x;                 // 1376, % 8 == 0 -> bijective
  int bid = blockIdx.x;
  int swz = (bid & 7) * (nwg >> 3) + (bid >> 3);
  const int ntn = N_DIM / 256;               // 43
  int mt = swz / ntn;
  int nt = swz % ntn;

  const int tid = threadIdx.x;
  const int w = tid >> 6;        // wave 0..7
  const int lane = tid & 63;
  const int wm = w >> 2;         // 0..1: M half (128 rows)
  const int wn = w & 3;          // 0..3: N quarter (64 cols)
  const int l31 = lane & 31;
  const int l5 = lane >> 5;
  const int r7 = l31 & 7;

  // staging: per-lane pre-swizzled global source (involution slot^row)
  const int srow = lane >> 3;
  const int sslot = (lane & 7) ^ srow;
  const size_t goff = (size_t)srow * K_DIM + (size_t)sslot * 8;
  const unsigned short* pA = Xb + (size_t)(mt * 256 + w * 16) * K_DIM + goff;
  const unsigned short* pB = Wt + (size_t)(nt * 256 + w * 16) * K_DIM + goff;

  // fragment base offsets (elements); frag addr = base ^ (ks*16)
  const int sw8 = (l5 ^ r7) << 3;
  const int aBase0 = (0 * 32 + l31) * 64 + sw8;
  const int aBase1 = (1 * 32 + l31) * 64 + sw8;
  const int aBase2 = (2 * 32 + l31) * 64 + sw8;
  const int aBase3 = (3 * 32 + l31) * 64 + sw8;
  const int bBase0 = ((wn & 1) * 64 + 0 * 32 + l31) * 64 + sw8;
  const int bBase1 = ((wn & 1) * 64 + 1 * 32 + l31) * 64 + sw8;

  f32x16 acc[4][2] = {};
  bf16x8 afr[4];
  bf16x8 bfr[2][4];

  // prologue: tile0 fully (buf0, 8 loads), tile1 B (buf1, 4 loads)
  STAGE(0, 0, 0, 0); STAGE(0, 0, 1, 0); STAGE(0, 1, 0, 0); STAGE(0, 1, 1, 0);
  STAGE(1, 1, 0, 1); STAGE(1, 1, 1, 1);
  WAIT_VM4;                       // tile0 done; tile1-B x4 in flight
  __builtin_amdgcn_s_barrier();
  asm volatile("" ::: "memory");

  // main loop: iteration i computes tiles 2i (buf0, P1-4) and 2i+1 (buf1, P5-8)
  for (int i = 0; i < 31; ++i) {
    int t = 2 * i;
    PHASE(0, { LOADB2(0, 0); LOADA(0, 0); }, STAGE(1, 0, 0, t + 1), NOSTMT,   LOADA(0, 1)); // P1
    PHASE(1, LOADB2(0, 1),                   STAGE(1, 0, 1, t + 1), NOSTMT,   LOADA(0, 2)); // P2
    PHASE(2, NOSTMT,                         STAGE(0, 1, 0, t + 2), NOSTMT,   LOADA(0, 3)); // P3
    PHASE(3, NOSTMT,                         STAGE(0, 1, 1, t + 2), WAIT_VM4, NOSTMT);      // P4
    PHASE(0, { LOADB2(1, 0); LOADA(1, 0); }, STAGE(0, 0, 0, t + 2), NOSTMT,   LOADA(1, 1)); // P5
    PHASE(1, LOADB2(1, 1),                   STAGE(0, 0, 1, t + 2), NOSTMT,   LOADA(1, 2)); // P6
    PHASE(2, NOSTMT,                         STAGE(1, 1, 0, t + 3), NOSTMT,   LOADA(1, 3)); // P7
    PHASE(3, NOSTMT,                         STAGE(1, 1, 1, t + 3), WAIT_VM4, NOSTMT);      // P8
  }
  // tail: tiles 62 (buf0) and 63 (buf1)
  PHASE(0, { LOADB2(0, 0); LOADA(0, 0); }, STAGE(1, 0, 0, 63), NOSTMT,   LOADA(0, 1));
  PHASE(1, LOADB2(0, 1),                   STAGE(1, 0, 1, 63), NOSTMT,   LOADA(0, 2));
  PHASE(2, NOSTMT,                         NOSTMT,             NOSTMT,   LOADA(0, 3));
  PHASE(3, NOSTMT,                         NOSTMT,             WAIT_VM0, NOSTMT);
  PHASE(0, { LOADB2(1, 0); LOADA(1, 0); }, NOSTMT,             NOSTMT,   LOADA(1, 1));
  PHASE(1, LOADB2(1, 1),                   NOSTMT,             NOSTMT,   LOADA(1, 2));
  PHASE(2, NOSTMT,                         NOSTMT,             NOSTMT,   LOADA(1, 3));
  PHASE(3, NOSTMT,                         NOSTMT,             NOSTMT,   NOSTMT);

  // epilogue: 32x32 C/D map: col = lane&31, row = (reg&3) + 8*(reg>>2) + 4*(lane>>5)
  const int r0 = mt * 256 + wm * 128;
  const int c0 = nt * 256 + wn * 64 + l31;
  #pragma unroll
  for (int nj = 0; nj < 2; ++nj) {
    int col = c0 + nj * 32;
    float bv = bias[col];
    #pragma unroll
    for (int mi = 0; mi < 4; ++mi) {
      #pragma unroll
      for (int reg = 0; reg < 16; ++reg) {
        int row = r0 + mi * 32 + (reg & 3) + 8 * (reg >> 2) + 4 * l5;
        out[(size_t)row * N_DIM + col] = acc[mi][nj][reg] + bv;
      }
    }
  }
}

// ---------------- fallback (ws too small): naive fp32 ----------------
__global__ void k_fallback(const float* __restrict__ x, const int* __restrict__ qw,
                           const int* __restrict__ qz, const float* __restrict__ sc,
                           const float* __restrict__ bias, float* __restrict__ out) {
  int n = blockIdx.x * blockDim.x + threadIdx.x;
  int m = blockIdx.y;
  const float* xr = x + (size_t)m * K_DIM;
  float acc = 0.f;
  for (int g = 0; g < 32; ++g) {
    float s = sc[g * N_DIM + n];
    int zq = (qz[g * (N_DIM / 8) + (n >> 3)] >> ((n & 7) * 4)) & 15;
    float zs = s * (float)zq;
    for (int k8 = g * 16; k8 < g * 16 + 16; ++k8) {
      int w = qw[(size_t)k8 * N_DIM + n];
      #pragma unroll
      for (int j = 0; j < 8; ++j) {
        float wf = s * (float)((w >> (4 * j)) & 15) - zs;
        acc += wf * xr[k8 * 8 + j];
      }
    }
  }
  out[(size_t)m * N_DIM + n] = acc + bias[n];
}

extern "C" void kernel_launch(void* const* d_in, const int* in_sizes, int n_in,
                              void* d_out, int out_size, void* d_ws, size_t ws_size,
                              hipStream_t stream) {
  const float* x  = (const float*)d_in[0];
  const int* qw   = (const int*)d_in[1];
  const int* qz   = (const int*)d_in[2];
  const float* sc = (const float*)d_in[3];
  const float* bias = (const float*)d_in[4];
  float* out = (float*)d_out;

  const size_t xb_bytes = (size_t)M_DIM * K_DIM * 2;
  const size_t wt_bytes = (size_t)N_DIM * K_DIM * 2;
  const size_t need = xb_bytes + wt_bytes;

  if (ws_size >= need) {
    unsigned short* xb = (unsigned short*)d_ws;
    unsigned short* wt = (unsigned short*)((char*)d_ws + xb_bytes);
    k_convert_x<<<dim3(4096), dim3(256), 0, stream>>>(x, xb);
    k_dequant_w<<<dim3(N_DIM / 256, 64), dim3(256), 0, stream>>>(qw, qz, sc, wt);
    k_gemm<<<dim3((M_DIM / 256) * (N_DIM / 256)), dim3(512), 0, stream>>>(xb, wt, bias, out);
  } else {
    k_fallback<<<dim3(N_DIM / 256, M_DIM), dim3(256), 0, stream>>>(x, qw, qz, sc, bias, out);
  }
}

// Round 5
// 716.100 us; speedup vs baseline: 1.0721x; 1.0721x over previous
//
#include <hip/hip_runtime.h>
#include <hip/hip_bf16.h>
#include <stdint.h>

// QuantLinear GPTQ 4-bit: out[8192,11008] = x[8192,4096] . W[4096,11008] + bias
#define M_DIM 8192
#define K_DIM 4096
#define N_DIM 11008

typedef __bf16 bf16x8 __attribute__((ext_vector_type(8)));
typedef float f32x4 __attribute__((ext_vector_type(4)));

typedef __attribute__((address_space(1))) const void global_cvoid;
typedef __attribute__((address_space(3))) void lds_void;

__device__ __forceinline__ unsigned short f2bf(float f) {
  unsigned int u = __float_as_uint(f);
  u += 0x7fffu + ((u >> 16) & 1u);
  return (unsigned short)(u >> 16);
}

__device__ __forceinline__ void gload_lds16(const void* g, void* l) {
  // async global->LDS: each lane's 16B lands at lds_base + lane*16 (linear dest)
  __builtin_amdgcn_global_load_lds((global_cvoid*)g, (lds_void*)l, 16, 0, 0);
}

// ---------------- stage 1: x fp32 -> bf16 ----------------
__global__ void k_convert_x(const float* __restrict__ x, unsigned short* __restrict__ xb) {
  const int nthreads = gridDim.x * blockDim.x;
  int tid = blockIdx.x * blockDim.x + threadIdx.x;
  const int n8 = (M_DIM * K_DIM) / 8;
  for (int i = tid; i < n8; i += nthreads) {
    const float4* p = (const float4*)x + (size_t)i * 2;
    float4 a = p[0], b = p[1];
    union { unsigned short h[8]; uint4 u; } r;
    r.h[0] = f2bf(a.x); r.h[1] = f2bf(a.y); r.h[2] = f2bf(a.z); r.h[3] = f2bf(a.w);
    r.h[4] = f2bf(b.x); r.h[5] = f2bf(b.y); r.h[6] = f2bf(b.z); r.h[7] = f2bf(b.w);
    ((uint4*)xb)[i] = r.u;
  }
}

// ---------------- stage 2: dequant W -> bf16 W^T [N][K] ----------------
__global__ void k_dequant_w(const int* __restrict__ qw, const int* __restrict__ qz,
                            const float* __restrict__ sc, unsigned short* __restrict__ wt) {
  int n = blockIdx.x * blockDim.x + threadIdx.x;
  int k8_0 = blockIdx.y * 8;
  int g = (k8_0 * 8) >> 7;
  float s = sc[g * N_DIM + n];
  int zq = (qz[g * (N_DIM / 8) + (n >> 3)] >> ((n & 7) * 4)) & 15;
  float zs = s * (float)zq;
  #pragma unroll
  for (int i = 0; i < 8; ++i) {
    int k8 = k8_0 + i;
    int w = qw[(size_t)k8 * N_DIM + n];
    union { unsigned short h[8]; uint4 u; } r;
    #pragma unroll
    for (int j = 0; j < 8; ++j) {
      float v = s * (float)((w >> (4 * j)) & 15) - zs;
      r.h[j] = f2bf(v);
    }
    *(uint4*)(wt + (size_t)n * K_DIM + (size_t)k8 * 8) = r.u;
  }
}

// ---------------- stage 3: 256x256 8-phase bf16 GEMM (round-2 + single-barrier) ----------------
// A = Xb [M][K], B = Wt [N][K]. 8 waves (2Mx4N), BK=64, dbuf swizzled LDS.
// Phase = {reads; stage-issue; lgkm(0); MFMA; [counted vmcnt]; s_barrier}.
// The pre-MFMA barrier of round 2 was redundant: every read targets a region
// published at an earlier END-barrier (tile 2i+1 at P4-end via vmcnt(4)->bar,
// tile 2i+2 at P8-end), and every stage is separated from its region's last
// reader by that reader's lgkmcnt(0) + >=1 end-barrier (audited all 8 slots).
// Swizzle: 16B slot ^= (row&7) on stage-source and reads (involution).

#define MFMA1(mi, nj, kk) \
  acc[mi][nj] = __builtin_amdgcn_mfma_f32_16x16x32_bf16(afr[(mi) & 1][kk], bfr[nj][kk], acc[mi][nj], 0, 0, 0)

#define MFMAQ(q) do { \
  __builtin_amdgcn_s_setprio(1); \
  MFMA1((q)*2+0, 0, 0); MFMA1((q)*2+0, 1, 0); MFMA1((q)*2+0, 2, 0); MFMA1((q)*2+0, 3, 0); \
  MFMA1((q)*2+1, 0, 0); MFMA1((q)*2+1, 1, 0); MFMA1((q)*2+1, 2, 0); MFMA1((q)*2+1, 3, 0); \
  MFMA1((q)*2+0, 0, 1); MFMA1((q)*2+0, 1, 1); MFMA1((q)*2+0, 2, 1); MFMA1((q)*2+0, 3, 1); \
  MFMA1((q)*2+1, 0, 1); MFMA1((q)*2+1, 1, 1); MFMA1((q)*2+1, 2, 1); MFMA1((q)*2+1, 3, 1); \
  __builtin_amdgcn_s_setprio(0); \
} while (0)

#define LOADA(buf, q) do { \
  const unsigned short* aa_ = sh + (((buf)*2)*2 + wm) * 8192 + (q) * 2048; \
  afr[0][0] = *(const bf16x8*)(const void*)(aa_ + aoff0); \
  afr[0][1] = *(const bf16x8*)(const void*)(aa_ + aoff1); \
  afr[1][0] = *(const bf16x8*)(const void*)(aa_ + 1024 + aoff0); \
  afr[1][1] = *(const bf16x8*)(const void*)(aa_ + 1024 + aoff1); \
} while (0)

#define LOADB(buf) do { \
  const unsigned short* bb_ = sh + (((buf)*2 + 1)*2 + (wn >> 1)) * 8192; \
  bfr[0][0] = *(const bf16x8*)(const void*)(bb_ + boff0); \
  bfr[0][1] = *(const bf16x8*)(const void*)(bb_ + boff1); \
  bfr[1][0] = *(const bf16x8*)(const void*)(bb_ + 1024 + boff0); \
  bfr[1][1] = *(const bf16x8*)(const void*)(bb_ + 1024 + boff1); \
  bfr[2][0] = *(const bf16x8*)(const void*)(bb_ + 2048 + boff0); \
  bfr[2][1] = *(const bf16x8*)(const void*)(bb_ + 2048 + boff1); \
  bfr[3][0] = *(const bf16x8*)(const void*)(bb_ + 3072 + boff0); \
  bfr[3][1] = *(const bf16x8*)(const void*)(bb_ + 3072 + boff1); \
} while (0)

#define STAGE(buf, ab, half, kt) do { \
  const unsigned short* g_ = ((ab) ? pB : pA) + ((size_t)(half) * 128) * K_DIM + (kt) * 64; \
  unsigned short* l_ = sh + ((((buf)*2 + (ab))*2 + (half)) * 8192) + w * 1024; \
  gload_lds16(g_, l_); \
  gload_lds16(g_ + 8 * K_DIM, l_ + 512); \
} while (0)

#define NOSTMT ((void)0)
#define WAIT_VM4 asm volatile("s_waitcnt vmcnt(4)" ::: "memory")
#define WAIT_VM0 asm volatile("s_waitcnt vmcnt(0)" ::: "memory")

// phase: reads | stage issue -> lgkm drain -> 16 MFMA -> [counted vmcnt] -> barrier
#define PHASE(buf, q, DOB, S1, VW) do { \
  LOADA(buf, q); \
  if (DOB) LOADB(buf); \
  S1; \
  asm volatile("s_waitcnt lgkmcnt(0)" ::: "memory"); \
  __builtin_amdgcn_sched_barrier(0); \
  MFMAQ(q); \
  VW; \
  __builtin_amdgcn_s_barrier(); \
  asm volatile("" ::: "memory"); \
} while (0)

__global__ __launch_bounds__(512, 2) void k_gemm(const unsigned short* __restrict__ Xb,
                                                 const unsigned short* __restrict__ Wt,
                                                 const float* __restrict__ bias,
                                                 float* __restrict__ out) {
  __shared__ __align__(16) unsigned short sh[2 * 2 * 2 * 8192];  // 128 KiB

  const int nwg = gridDim.x;                 // 1376, % 8 == 0 -> bijective
  int bid = blockIdx.x;
  int swz = (bid & 7) * (nwg >> 3) + (bid >> 3);
  const int ntn = N_DIM / 256;               // 43
  int mt = swz / ntn;
  int nt = swz % ntn;

  const int tid = threadIdx.x;
  const int w = tid >> 6;        // wave 0..7
  const int lane = tid & 63;
  const int wm = w >> 2;         // 0..1 (M sub-tile 128)
  const int wn = w & 3;          // 0..3 (N sub-tile 64)
  const int fr = lane & 15;
  const int fq = lane >> 4;

  // staging: per-lane pre-swizzled global source (involution slot^row)
  const int srow = lane >> 3;                 // 0..7
  const int sslot = (lane & 7) ^ srow;        // 16B slot in the 128B row
  const size_t goff = (size_t)srow * K_DIM + (size_t)sslot * 8;
  const unsigned short* pA = Xb + (size_t)(mt * 256 + w * 16) * K_DIM + goff;
  const unsigned short* pB = Wt + (size_t)(nt * 256 + w * 16) * K_DIM + goff;

  // ds_read element offsets (swizzled slot = (kk*4+fq) ^ (row&7), row&7 == fr&7)
  const int aoff0 = fr * 64 + ((fq) ^ (fr & 7)) * 8;
  const int aoff1 = fr * 64 + ((4 + fq) ^ (fr & 7)) * 8;
  const int boff0 = ((wn & 1) * 64 + fr) * 64 + ((fq) ^ (fr & 7)) * 8;
  const int boff1 = ((wn & 1) * 64 + fr) * 64 + ((4 + fq) ^ (fr & 7)) * 8;

  f32x4 acc[8][4] = {};
  bf16x8 afr[2][2];
  bf16x8 bfr[4][2];

  // prologue: tile0 fully (buf0), tile1 B-halves (buf1)
  STAGE(0, 0, 0, 0); STAGE(0, 0, 1, 0); STAGE(0, 1, 0, 0); STAGE(0, 1, 1, 0);
  STAGE(1, 1, 0, 1); STAGE(1, 1, 1, 1);
  WAIT_VM4;                       // tile0's 8 loads done; B(1) x4 in flight
  __builtin_amdgcn_s_barrier();
  asm volatile("" ::: "memory");

  // main loop: iteration computes tiles 2i (buf0, P1-4) and 2i+1 (buf1, P5-8)
  for (int i = 0; i < 31; ++i) {
    int t = 2 * i;
    PHASE(0, 0, true,  STAGE(1, 0, 0, t + 1), NOSTMT);   // P1
    PHASE(0, 1, false, STAGE(1, 0, 1, t + 1), NOSTMT);   // P2
    PHASE(0, 2, false, STAGE(0, 1, 0, t + 2), NOSTMT);   // P3
    PHASE(0, 3, false, STAGE(0, 1, 1, t + 2), WAIT_VM4); // P4: tile 2i+1 ready
    PHASE(1, 0, true,  STAGE(0, 0, 0, t + 2), NOSTMT);   // P5
    PHASE(1, 1, false, STAGE(0, 0, 1, t + 2), NOSTMT);   // P6
    PHASE(1, 2, false, STAGE(1, 1, 0, t + 3), NOSTMT);   // P7
    PHASE(1, 3, false, STAGE(1, 1, 1, t + 3), WAIT_VM4); // P8: tile 2i+2 ready
  }
  // final iteration: tiles 62 (buf0), 63 (buf1); drain
  PHASE(0, 0, true,  STAGE(1, 0, 0, 63), NOSTMT);
  PHASE(0, 1, false, STAGE(1, 0, 1, 63), NOSTMT);
  PHASE(0, 2, false, NOSTMT, NOSTMT);
  PHASE(0, 3, false, NOSTMT, WAIT_VM0);
  PHASE(1, 0, true,  NOSTMT, NOSTMT);
  PHASE(1, 1, false, NOSTMT, NOSTMT);
  PHASE(1, 2, false, NOSTMT, NOSTMT);
  PHASE(1, 3, false, NOSTMT, NOSTMT);

  // epilogue: C/D layout col=lane&15, row=(lane>>4)*4+reg
  const int r0 = mt * 256 + wm * 128 + fq * 4;
  const int c0 = nt * 256 + wn * 64 + fr;
  #pragma unroll
  for (int nj = 0; nj < 4; ++nj) {
    int col = c0 + nj * 16;
    float bv = bias[col];
    #pragma unroll
    for (int mi = 0; mi < 8; ++mi) {
      size_t base = (size_t)(r0 + mi * 16) * N_DIM + col;
      #pragma unroll
      for (int r = 0; r < 4; ++r)
        out[base + (size_t)r * N_DIM] = acc[mi][nj][r] + bv;
    }
  }
}

// ---------------- fallback (ws too small): naive fp32 ----------------
__global__ void k_fallback(const float* __restrict__ x, const int* __restrict__ qw,
                           const int* __restrict__ qz, const float* __restrict__ sc,
                           const float* __restrict__ bias, float* __restrict__ out) {
  int n = blockIdx.x * blockDim.x + threadIdx.x;
  int m = blockIdx.y;
  const float* xr = x + (size_t)m * K_DIM;
  float acc = 0.f;
  for (int g = 0; g < 32; ++g) {
    float s = sc[g * N_DIM + n];
    int zq = (qz[g * (N_DIM / 8) + (n >> 3)] >> ((n & 7) * 4)) & 15;
    float zs = s * (float)zq;
    for (int k8 = g * 16; k8 < g * 16 + 16; ++k8) {
      int w = qw[(size_t)k8 * N_DIM + n];
      #pragma unroll
      for (int j = 0; j < 8; ++j) {
        float wf = s * (float)((w >> (4 * j)) & 15) - zs;
        acc += wf * xr[k8 * 8 + j];
      }
    }
  }
  out[(size_t)m * N_DIM + n] = acc + bias[n];
}

extern "C" void kernel_launch(void* const* d_in, const int* in_sizes, int n_in,
                              void* d_out, int out_size, void* d_ws, size_t ws_size,
                              hipStream_t stream) {
  const float* x  = (const float*)d_in[0];
  const int* qw   = (const int*)d_in[1];
  const int* qz   = (const int*)d_in[2];
  const float* sc = (const float*)d_in[3];
  const float* bias = (const float*)d_in[4];
  float* out = (float*)d_out;

  const size_t xb_bytes = (size_t)M_DIM * K_DIM * 2;
  const size_t wt_bytes = (size_t)N_DIM * K_DIM * 2;
  const size_t need = xb_bytes + wt_bytes;

  if (ws_size >= need) {
    unsigned short* xb = (unsigned short*)d_ws;
    unsigned short* wt = (unsigned short*)((char*)d_ws + xb_bytes);
    k_convert_x<<<dim3(4096), dim3(256), 0, stream>>>(x, xb);
    k_dequant_w<<<dim3(N_DIM / 256, 64), dim3(256), 0, stream>>>(qw, qz, sc, wt);
    k_gemm<<<dim3((M_DIM / 256) * (N_DIM / 256)), dim3(512), 0, stream>>>(xb, wt, bias, out);
  } else {
    k_fallback<<<dim3(N_DIM / 256, M_DIM), dim3(256), 0, stream>>>(x, qw, qz, sc, bias, out);
  }
}